// Round 8
// baseline (458.144 us; speedup 1.0000x reference)
//
#include <hip/hip_runtime.h>
#include <hip/hip_bf16.h>
#include <cstring>

// Problem constants: B=2, X=96, Y=96, Z=64, C=32, K=16, LOG_PROB_SCALE=200
#define NVOX (2 * 96 * 96 * 64)
#define K_TOT 16
#define N_TILES (NVOX / 128)   // 9216 tiles of 128 voxels
#define N_BLOCKS 512           // 2 resident blocks/CU at waves_per_eu=2
#define N_WAVES_G 2048         // 512 blocks x 4 waves; grid-stride 4-5 tiles/wave

typedef __attribute__((ext_vector_type(8)))  short short8;   // 8 bf16 (A/B frag)
typedef __attribute__((ext_vector_type(16))) float f32x16;   // C/D frag
typedef __attribute__((ext_vector_type(2)))  float f32x2;
typedef __attribute__((ext_vector_type(2)))  unsigned int uint2v;

// g_ws layout (module-scope device global; d_ws unused):
//   bytes [0, 32768): A-frags bf16, ushort idx ((kc*2 + half)*64 + lane)*8 + j
//       = Linv[kc][m = lane&31][c = half*16 + (lane>>5)*8 + j]
//   floats [8192, 8704): uf[kc*32 + (lane>>5)*16 + reg] = -u_kc[(reg&3)+8*(reg>>2)+4*(lane>>5)]
//   floats [8704, 8736): pairs (h2[kc], w[kc]); h2 = log2e*(const - logdet)/200
#define WS_UF 8192
#define WS_HW 8704
#define WS_FLOATS 8736   // 34944 bytes

__device__ __align__(16) float g_ws[WS_FLOATS];

static __device__ __forceinline__ unsigned short f2b(float f) {
    __hip_bfloat16 h = __float2bfloat16(f);
    unsigned short u;
    __builtin_memcpy(&u, &h, 2);
    return u;
}

// Pack two f32 into a dword of two bf16 (round-half-up): 2x v_add_u32 + v_perm_b32.
static __device__ __forceinline__ int pack2_bf16(float f0, float f1) {
    unsigned a, b;
    __builtin_memcpy(&a, &f0, 4);
    __builtin_memcpy(&b, &f1, 4);
    return (int)__builtin_amdgcn_perm(b + 0x8000u, a + 0x8000u, 0x07060302u);
}

static __device__ __forceinline__ short8 cvt8(float4 lo, float4 hi) {
    int p0 = pack2_bf16(lo.x, lo.y);
    int p1 = pack2_bf16(lo.z, lo.w);
    int p2 = pack2_bf16(hi.x, hi.y);
    int p3 = pack2_bf16(hi.z, hi.w);
    int v[4] = {p0, p1, p2, p3};
    short8 r;
    __builtin_memcpy(&r, v, 16);
    return r;
}

// readfirstlane for float (value is wave-uniform; pins it into an SGPR)
static __device__ __forceinline__ float rfl(float x) {
    int i;
    __builtin_memcpy(&i, &x, 4);
    i = __builtin_amdgcn_readfirstlane(i);
    float r;
    __builtin_memcpy(&r, &i, 4);
    return r;
}

// Sum p across the two 32-lane halves: returns p[lane] + p[lane^32] in every
// lane. permlane32_swap builtin (VALU-only; correctness verified r2-r6).
static __device__ __forceinline__ float cross_half_sum(float p) {
#if __has_builtin(__builtin_amdgcn_permlane32_swap)
    unsigned pu;
    __builtin_memcpy(&pu, &p, 4);
    uint2v r = __builtin_amdgcn_permlane32_swap(pu, pu, false, false);
    unsigned a = r.x, b = r.y;
    float fa, fb;
    __builtin_memcpy(&fa, &a, 4);
    __builtin_memcpy(&fb, &b, 4);
    return fa + fb;   // {lo,lo} + {hi,hi} in each lane = p + p[lane^32]
#else
    return p + __shfl_xor(p, 32);
#endif
}

__global__ void gmm_prep_kernel(const float* __restrict__ wb, const float* __restrict__ mb,
                                const float* __restrict__ Lb, const float* __restrict__ wf,
                                const float* __restrict__ mf, const float* __restrict__ Lf) {
    int k   = blockIdx.x;   // component
    int tid = threadIdx.x;  // 64 threads

    __shared__ float Lsh[1024];   // L_k row-major
    __shared__ float Lish[1024];  // Linv_k row-major (upper tri = 0)
    __shared__ float ush[32];     // u = Linv * mu

    const float* L  = (k < 8) ? (Lb + k * 1024) : (Lf + (k - 8) * 1024);
    const float* mu = (k < 8) ? (mb + k * 32)   : (mf + (k - 8) * 32);

    for (int i = tid; i < 1024; i += 64) Lsh[i] = L[i];
    __syncthreads();

    if (tid < 32) {
        int j = tid;  // solve column j: L * col = e_j
        float col[32];
#pragma unroll
        for (int i = 0; i < 32; ++i) {
            float s = (i == j) ? 1.0f : 0.0f;
#pragma unroll
            for (int m = 0; m < i; ++m) s = fmaf(-Lsh[i * 32 + m], col[m], s);
            float val = s / Lsh[i * 32 + i];
            col[i] = (i >= j) ? val : 0.0f;
        }
#pragma unroll
        for (int i = 0; i < 32; ++i) Lish[i * 32 + j] = col[i];
    }
    __syncthreads();
    if (tid < 32) {
        int d = tid;
        float s = 0.0f;
        for (int c = 0; c <= d; ++c) s = fmaf(Lish[d * 32 + c], mu[c], s);
        ush[d] = s;
    }
    __syncthreads();

    // A-fragments in MFMA 32x32x16 operand order, bf16 (RNE; prep is cold).
    unsigned short* wsA = (unsigned short*)g_ws;
    int m  = tid & 31;   // outdim row
    int kq = tid >> 5;   // k-half-of-8 within the MFMA's K=16
#pragma unroll
    for (int hf = 0; hf < 2; ++hf) {  // channel halves 0..15 / 16..31
        unsigned short* dst = wsA + (size_t)(((k * 2 + hf) * 64 + tid) * 8);
#pragma unroll
        for (int j = 0; j < 8; ++j)
            dst[j] = f2b(Lish[m * 32 + hf * 16 + kq * 8 + j]);
    }
    // -u in C/D fragment order
    if (tid < 32) {
        int h = tid >> 4, r = tid & 15;
        g_ws[WS_UF + k * 32 + tid] = -ush[(r & 3) + 8 * (r >> 2) + 4 * h];
    }
    if (tid == 0) {
        float ld = 0.0f;
        for (int i = 0; i < 32; ++i) ld += logf(Lsh[i * 32 + i]);
        const float cconst = -0.5f * 32.0f * 1.8378770664093453f;  // -C/2*log(2pi)
        const float log2e  = 1.4426950408889634f;
        g_ws[WS_HW + k * 2]     = (cconst - ld) * (1.0f / 200.0f) * log2e;
        g_ws[WS_HW + k * 2 + 1] = (k < 8) ? wb[k] : wf[k - 8];
    }
}

// ---- hot-path macros: only named variables, no arrays, no lambdas ----------

// Load one PAIR of groups (2x32 voxels, this half-wave's channel slices):
// 8 float4 into r0..r7 (32 VGPRs in flight — max pipeline state by design;
// r6 post-mortem: >100 frag/raw regs live -> allocator spills wholesale).
#define LOADP(tile, pr) do {                                                  \
    const float* x0_ = fm + (((size_t)(tile) * 128 + ((pr) * 2 + 0) * 32 + c) * 32 + h * 8); \
    r0 = *(const float4*)(x0_ + 0);  r1 = *(const float4*)(x0_ + 4);          \
    r2 = *(const float4*)(x0_ + 16); r3 = *(const float4*)(x0_ + 20);         \
    const float* x1_ = fm + (((size_t)(tile) * 128 + ((pr) * 2 + 1) * 32 + c) * 32 + h * 8); \
    r4 = *(const float4*)(x1_ + 0);  r5 = *(const float4*)(x1_ + 4);          \
    r6 = *(const float4*)(x1_ + 16); r7 = *(const float4*)(x1_ + 20);         \
} while (0)

// Convert the landed pair into the two live B-fragments (raw dies here).
#define CVTP() do {                                                           \
    B0l = cvt8(r0, r1); B0h = cvt8(r2, r3);                                   \
    B1l = cvt8(r4, r5); B1h = cvt8(r6, r7);                                   \
} while (0)

// One output group: 2 MFMA + packed sum-of-squares + cross-half + exp2-acc
#define KG(Bl, Bh, dd, h2v, wkv) do {                                         \
    f32x16 dt_ = __builtin_amdgcn_mfma_f32_32x32x16_bf16(Alo_, Bl, Cu_, 0, 0, 0); \
    dt_ = __builtin_amdgcn_mfma_f32_32x32x16_bf16(Ahi_, Bh, dt_, 0, 0, 0);    \
    const f32x2* dp_ = (const f32x2*)&dt_;                                    \
    f32x2 q0_ = dp_[0] * dp_[0];                                              \
    f32x2 q1_ = dp_[1] * dp_[1];                                              \
    q0_ += dp_[2] * dp_[2];  q1_ += dp_[3] * dp_[3];                          \
    q0_ += dp_[4] * dp_[4];  q1_ += dp_[5] * dp_[5];                          \
    q0_ += dp_[6] * dp_[6];  q1_ += dp_[7] * dp_[7];                          \
    f32x2 qs_ = q0_ + q1_;                                                    \
    float p_ = qs_[0] + qs_[1];                                               \
    float pt_ = cross_half_sum(p_);                                           \
    dd = fmaf(wkv, __builtin_amdgcn_exp2f(fmaf(pt_, SCALE, h2v)), dd);        \
} while (0)

// One K-step over the CURRENT PAIR (B0,B1), accumulating into (da,db).
#define KSTEP2(kc, da, db) do {                                               \
    const short8 Alo_ = *(const short8*)(sWf + ((size_t)((kc) * 2 + 0) * 64 + lane) * 8); \
    const short8 Ahi_ = *(const short8*)(sWf + ((size_t)((kc) * 2 + 1) * 64 + lane) * 8); \
    const f32x16 Cu_  = *(const f32x16*)(sUf + (kc) * 32 + h * 16);           \
    KG(B0l, B0h, da, h2_##kc, wk_##kc);                                       \
    KG(B1l, B1h, db, h2_##kc, wk_##kc);                                       \
} while (0)

// Full component sweep for one pair (~1600 issue-cycles of load cover).
#define PASS(da, db) do {                                                     \
    KSTEP2(0, da, db);  KSTEP2(1, da, db);  KSTEP2(2, da, db);  KSTEP2(3, da, db);  \
    KSTEP2(4, da, db);  KSTEP2(5, da, db);  KSTEP2(6, da, db);  KSTEP2(7, da, db);  \
    KSTEP2(8, da, db);  KSTEP2(9, da, db);  KSTEP2(10, da, db); KSTEP2(11, da, db); \
    KSTEP2(12, da, db); KSTEP2(13, da, db); KSTEP2(14, da, db); KSTEP2(15, da, db); \
} while (0)

#define DECL_HW(i)                                                            \
    const float h2_##i = rfl(sHW[(i) * 2]);                                   \
    const float wk_##i = rfl(sHW[(i) * 2 + 1]);

// Grid-stride, pair-granular software pipeline at __launch_bounds__(256,2).
// Why (256,2): unified-file even split (r2-r6: VGPR_Count = exactly half the
// budget: 84 @ (256,3), 128 @ (256,2)) -> 128 arch VGPRs here.
// Why pair-granular: nominal peak live set = B-pair 16 + raw 32 + d 4 +
// A/Cu 24 + addr ~12 = 88 regs — fits 128 even with the ~30-reg scheduler
// slop that sank the tile-granular variants (r1/r3/r4/r6).
// Steady state: every wave permanently holds 8 loads (8 KB) in flight under
// a full 16-component PASS (~1600 cyc) — continuous HBM duty cycle.
// Cost accepted: A/Cu LDS reads are re-done per pass (2x: 192 ds_read_b128
// per tile-wave ~ 11.5 us/CU aggregate, below the 25 us HBM floor).
__global__ __launch_bounds__(256, 2) void gmm_density_kernel(
        const float* __restrict__ fm, float* __restrict__ out) {
    __shared__ __align__(16) float smem[WS_FLOATS];   // 34.9 KB
    {
        const float4* src = (const float4*)g_ws;
        float4* dst = (float4*)smem;
        for (int i = threadIdx.x; i < WS_FLOATS / 4; i += 256) dst[i] = src[i];
    }
    __syncthreads();
    const unsigned short* sWf = (const unsigned short*)smem;
    const float* sUf = smem + WS_UF;
    const float* sHW = smem + WS_HW;

    const int lane = threadIdx.x & 63;
    const int c    = lane & 31;   // voxel within 32-group / D-tile column
    const int h    = lane >> 5;   // half-wave
    const int wid  = (blockIdx.x * 256 + (int)threadIdx.x) >> 6;  // 0..2047

    const float SCALE = -0.0036067376022224085f;  // -log2(e)/400

    // Per-component uniforms -> SGPRs, individually named.
    DECL_HW(0)  DECL_HW(1)  DECL_HW(2)  DECL_HW(3)
    DECL_HW(4)  DECL_HW(5)  DECL_HW(6)  DECL_HW(7)
    DECL_HW(8)  DECL_HW(9)  DECL_HW(10) DECL_HW(11)
    DECL_HW(12) DECL_HW(13) DECL_HW(14) DECL_HW(15)

    // Pipeline state: one B-pair + one raw pair. Nothing else.
    short8 B0l, B0h, B1l, B1h;
    float4 r0, r1, r2, r3, r4, r5, r6, r7;

    // prologue
    int t = wid;
    LOADP(t, 0);
    CVTP();
    LOADP(t, 1);

    while (true) {
        float d0 = 0.f, d1 = 0.f, d2 = 0.f, d3 = 0.f;
        const int nt = t + N_WAVES_G;
        const bool more = (nt < N_TILES);   // wave-uniform

        PASS(d0, d1);            // groups 0,1 of t; pair1 loads in flight
        CVTP();                  // pair1 -> B (raw dies)
        if (more) LOADP(nt, 0);  // next tile's pair0 into raw
        PASS(d2, d3);            // groups 2,3 of t; next pair0 in flight

        // Store: half-wave h writes groups {2h, 2h+1}; zero the z==63 slice
        // (z = (g*32 + c) & 63 == 63  <=>  c==31 && g odd).
        {
            size_t vbase = (size_t)t * 128;
            float v0 = h ? d2 : d0;
            float v1 = h ? d3 : d1;
            if (c == 31) v1 = 0.f;
            out[vbase + (size_t)(h * 2 + 0) * 32 + c] = v0;
            out[vbase + (size_t)(h * 2 + 1) * 32 + c] = v1;
        }

        if (!more) break;
        CVTP();                  // next pair0 -> B
        LOADP(nt, 1);            // next pair1 into raw
        t = nt;
    }
}

extern "C" void kernel_launch(void* const* d_in, const int* in_sizes, int n_in,
                              void* d_out, int out_size, void* d_ws, size_t ws_size,
                              hipStream_t stream) {
    const float* fm = (const float*)d_in[0];
    const float* wb = (const float*)d_in[1];
    const float* mb = (const float*)d_in[2];
    const float* Lb = (const float*)d_in[3];
    const float* wf = (const float*)d_in[4];
    const float* mf = (const float*)d_in[5];
    const float* Lf = (const float*)d_in[6];
    float* out = (float*)d_out;
    (void)d_ws; (void)ws_size;   // staging lives in g_ws (module device global)

    gmm_prep_kernel<<<K_TOT, 64, 0, stream>>>(wb, mb, Lb, wf, mf, Lf);
    gmm_density_kernel<<<N_BLOCKS, 256, 0, stream>>>(fm, out);
}

// Round 9
// 255.580 us; speedup vs baseline: 1.7926x; 1.7926x over previous
//
#include <hip/hip_runtime.h>
#include <hip/hip_bf16.h>
#include <cstring>

// Problem constants: B=2, X=96, Y=96, Z=64, C=32, K=16, LOG_PROB_SCALE=200
#define NVOX (2 * 96 * 96 * 64)
#define K_TOT 16
#define N_TILES (NVOX / 128)   // 9216 tiles of 128 voxels
#define N_BLOCKS 256           // 1 block/CU (LDS-capped); persistent grid-stride
#define WAVES_PB 7             // 448 threads; LDS = 35 KB ws + 7 x 16 KB slabs
#define THREADS (WAVES_PB * 64)
#define N_WAVES_G (N_BLOCKS * WAVES_PB)   // 1792 waves; 5-6 tiles/wave
#define SLAB_FLOATS 4096       // 16 KB per-wave staging slab

typedef __attribute__((ext_vector_type(8)))  short short8;   // 8 bf16 (A/B frag)
typedef __attribute__((ext_vector_type(16))) float f32x16;   // C/D frag
typedef __attribute__((ext_vector_type(2)))  float f32x2;
typedef __attribute__((ext_vector_type(2)))  unsigned int uint2v;

// g_ws layout (module-scope device global; d_ws unused):
//   bytes [0, 32768): A-frags bf16, ushort idx ((kc*2 + half)*64 + lane)*8 + j
//       = Linv[kc][m = lane&31][c = half*16 + (lane>>5)*8 + j]
//   floats [8192, 8704): uf[kc*32 + (lane>>5)*16 + reg] = -u_kc[(reg&3)+8*(reg>>2)+4*(lane>>5)]
//   floats [8704, 8736): pairs (h2[kc], w[kc]); h2 = log2e*(const - logdet)/200
#define WS_UF 8192
#define WS_HW 8704
#define WS_FLOATS 8736   // 34944 bytes

__device__ __align__(16) float g_ws[WS_FLOATS];

static __device__ __forceinline__ unsigned short f2b(float f) {
    __hip_bfloat16 h = __float2bfloat16(f);
    unsigned short u;
    __builtin_memcpy(&u, &h, 2);
    return u;
}

// Pack two f32 into a dword of two bf16 (round-half-up): 2x v_add_u32 + v_perm_b32.
static __device__ __forceinline__ int pack2_bf16(float f0, float f1) {
    unsigned a, b;
    __builtin_memcpy(&a, &f0, 4);
    __builtin_memcpy(&b, &f1, 4);
    return (int)__builtin_amdgcn_perm(b + 0x8000u, a + 0x8000u, 0x07060302u);
}

static __device__ __forceinline__ short8 cvt8(float4 lo, float4 hi) {
    int p0 = pack2_bf16(lo.x, lo.y);
    int p1 = pack2_bf16(lo.z, lo.w);
    int p2 = pack2_bf16(hi.x, hi.y);
    int p3 = pack2_bf16(hi.z, hi.w);
    int v[4] = {p0, p1, p2, p3};
    short8 r;
    __builtin_memcpy(&r, v, 16);
    return r;
}

// Sum p across the two 32-lane halves: returns p[lane] + p[lane^32] in every
// lane. permlane32_swap builtin (VALU-only; correctness verified r2-r8).
static __device__ __forceinline__ float cross_half_sum(float p) {
#if __has_builtin(__builtin_amdgcn_permlane32_swap)
    unsigned pu;
    __builtin_memcpy(&pu, &p, 4);
    uint2v r = __builtin_amdgcn_permlane32_swap(pu, pu, false, false);
    unsigned a = r.x, b = r.y;
    float fa, fb;
    __builtin_memcpy(&fa, &a, 4);
    __builtin_memcpy(&fb, &b, 4);
    return fa + fb;   // {lo,lo} + {hi,hi} in each lane = p + p[lane^32]
#else
    return p + __shfl_xor(p, 32);
#endif
}

// HBM -> LDS direct DMA, 16 B per lane. Global source is PER-LANE; LDS dest is
// wave-uniform base + lane*16 (HW rule, m104). Zero VGPRs held in flight —
// this is the mechanism that ends the r1/r3/r4/r6/r8 spill pathology.
static __device__ __forceinline__ void gl_lds16(const float* g, float* l) {
    __builtin_amdgcn_global_load_lds(
        (const __attribute__((address_space(1))) void*)g,
        (__attribute__((address_space(3))) void*)l,
        16, 0, 0);
}

__global__ void gmm_prep_kernel(const float* __restrict__ wb, const float* __restrict__ mb,
                                const float* __restrict__ Lb, const float* __restrict__ wf,
                                const float* __restrict__ mf, const float* __restrict__ Lf) {
    int k   = blockIdx.x;   // component
    int tid = threadIdx.x;  // 64 threads

    __shared__ float Lsh[1024];   // L_k row-major
    __shared__ float Lish[1024];  // Linv_k row-major (upper tri = 0)
    __shared__ float ush[32];     // u = Linv * mu

    const float* L  = (k < 8) ? (Lb + k * 1024) : (Lf + (k - 8) * 1024);
    const float* mu = (k < 8) ? (mb + k * 32)   : (mf + (k - 8) * 32);

    for (int i = tid; i < 1024; i += 64) Lsh[i] = L[i];
    __syncthreads();

    if (tid < 32) {
        int j = tid;  // solve column j: L * col = e_j
        float col[32];
#pragma unroll
        for (int i = 0; i < 32; ++i) {
            float s = (i == j) ? 1.0f : 0.0f;
#pragma unroll
            for (int m = 0; m < i; ++m) s = fmaf(-Lsh[i * 32 + m], col[m], s);
            float val = s / Lsh[i * 32 + i];
            col[i] = (i >= j) ? val : 0.0f;
        }
#pragma unroll
        for (int i = 0; i < 32; ++i) Lish[i * 32 + j] = col[i];
    }
    __syncthreads();
    if (tid < 32) {
        int d = tid;
        float s = 0.0f;
        for (int c = 0; c <= d; ++c) s = fmaf(Lish[d * 32 + c], mu[c], s);
        ush[d] = s;
    }
    __syncthreads();

    // A-fragments in MFMA 32x32x16 operand order, bf16 (RNE; prep is cold).
    unsigned short* wsA = (unsigned short*)g_ws;
    int m  = tid & 31;   // outdim row
    int kq = tid >> 5;   // k-half-of-8 within the MFMA's K=16
#pragma unroll
    for (int hf = 0; hf < 2; ++hf) {  // channel halves 0..15 / 16..31
        unsigned short* dst = wsA + (size_t)(((k * 2 + hf) * 64 + tid) * 8);
#pragma unroll
        for (int j = 0; j < 8; ++j)
            dst[j] = f2b(Lish[m * 32 + hf * 16 + kq * 8 + j]);
    }
    // -u in C/D fragment order
    if (tid < 32) {
        int h = tid >> 4, r = tid & 15;
        g_ws[WS_UF + k * 32 + tid] = -ush[(r & 3) + 8 * (r >> 2) + 4 * h];
    }
    if (tid == 0) {
        float ld = 0.0f;
        for (int i = 0; i < 32; ++i) ld += logf(Lsh[i * 32 + i]);
        const float cconst = -0.5f * 32.0f * 1.8378770664093453f;  // -C/2*log(2pi)
        const float log2e  = 1.4426950408889634f;
        g_ws[WS_HW + k * 2]     = (cconst - ld) * (1.0f / 200.0f) * log2e;
        g_ws[WS_HW + k * 2 + 1] = (k < 8) ? wb[k] : wf[k - 8];
    }
}

// r0's proven no-spill compute structure (kc-outer, 4 groups, 84-reg live set)
// with the B-frag staging moved to global_load_lds -> per-wave private 16 KB
// LDS slab. Pipeline: next tile's 16 DMA loads are issued right after this
// tile's cvt and stay in flight under the ~2300-cyc kc-loop. No __syncthreads
// in the loop (slab is wave-private); explicit vmcnt/lgkmcnt fences instead.
// 7 waves x 16 KB continuously in flight per CU >> HBM demand -> BW roofline.
__global__ __launch_bounds__(THREADS, 2) void gmm_density_kernel(
        const float* __restrict__ fm, float* __restrict__ out) {
    __shared__ __align__(16) float smem[WS_FLOATS + WAVES_PB * SLAB_FLOATS]; // 149.6 KB
    {
        const float4* src = (const float4*)g_ws;
        float4* dst = (float4*)smem;
        for (int i = threadIdx.x; i < WS_FLOATS / 4; i += THREADS) dst[i] = src[i];
    }
    __syncthreads();
    const unsigned short* sWf = (const unsigned short*)smem;
    const float* sUf = smem + WS_UF;
    const float* sHW = smem + WS_HW;

    const int lane = threadIdx.x & 63;
    const int c    = lane & 31;   // voxel within 32-group / D-tile column
    const int h    = lane >> 5;   // half-wave
    const int wv   = threadIdx.x >> 6;             // wave in block (0..6)
    float* slab    = smem + WS_FLOATS + wv * SLAB_FLOATS;  // wave-private 16 KB
    const int wid  = blockIdx.x * WAVES_PB + wv;   // 0..1791

    const float SCALE = -0.0036067376022224085f;  // -log2(e)/400

    // Issue the 16 DMA loads for tile `tile` into this wave's slab.
    // Load ld = g*4+j lands at slab[ld*256 + lane*4] (16 B/lane, HW layout).
#define ISSUE_TILE(tile) do {                                                 \
        _Pragma("unroll")                                                     \
        for (int g_ = 0; g_ < 4; ++g_) {                                      \
            const float* xb_ = fm + (((size_t)(tile) * 128 + g_ * 32 + c) * 32 + h * 8); \
            gl_lds16(xb_ + 0,  slab + (g_ * 4 + 0) * 256);                    \
            gl_lds16(xb_ + 4,  slab + (g_ * 4 + 1) * 256);                    \
            gl_lds16(xb_ + 16, slab + (g_ * 4 + 2) * 256);                    \
            gl_lds16(xb_ + 20, slab + (g_ * 4 + 3) * 256);                    \
        }                                                                     \
    } while (0)

    int t = wid;
    ISSUE_TILE(t);   // prologue: first tile's loads in flight

    short8 Blo[4], Bhi[4];
    while (true) {
        const int nt = t + N_WAVES_G;
        const bool more = (nt < N_TILES);   // wave-uniform

        // Wait for this tile's DMA to land, then pull slab -> B fragments.
        asm volatile("s_waitcnt vmcnt(0)" ::: "memory");
        __builtin_amdgcn_sched_barrier(0);
#pragma unroll
        for (int g = 0; g < 4; ++g) {
            float4 a0 = *(const float4*)(slab + (g * 4 + 0) * 256 + lane * 4);
            float4 a1 = *(const float4*)(slab + (g * 4 + 1) * 256 + lane * 4);
            float4 b0 = *(const float4*)(slab + (g * 4 + 2) * 256 + lane * 4);
            float4 b1 = *(const float4*)(slab + (g * 4 + 3) * 256 + lane * 4);
            Blo[g] = cvt8(a0, a1);
            Bhi[g] = cvt8(b0, b1);
        }
        // Slab fully consumed into regs; safe to reissue into it (drain the
        // ds_reads first so the incoming DMA writes can't race them).
        asm volatile("s_waitcnt lgkmcnt(0)" ::: "memory");
        __builtin_amdgcn_sched_barrier(0);
        if (more) ISSUE_TILE(nt);
        __builtin_amdgcn_sched_barrier(0);

        // kc-loop: identical to the proven r0 structure (84-reg, no spill).
        float dens[4] = {0.f, 0.f, 0.f, 0.f};
        for (int kc = 0; kc < K_TOT; ++kc) {
            short8 Alo = *(const short8*)(sWf + ((size_t)(kc * 2 + 0) * 64 + lane) * 8);
            short8 Ahi = *(const short8*)(sWf + ((size_t)(kc * 2 + 1) * 64 + lane) * 8);
            f32x16 Cu = *(const f32x16*)(sUf + kc * 32 + h * 16);
            float h2 = sHW[kc * 2], wk = sHW[kc * 2 + 1];
#pragma unroll
            for (int g = 0; g < 4; ++g) {
                f32x16 d = __builtin_amdgcn_mfma_f32_32x32x16_bf16(Alo, Blo[g], Cu, 0, 0, 0);
                d = __builtin_amdgcn_mfma_f32_32x32x16_bf16(Ahi, Bhi[g], d, 0, 0, 0);
                const f32x2* dp = (const f32x2*)&d;
                f32x2 acc0 = dp[0] * dp[0];
                f32x2 acc1 = dp[1] * dp[1];
#pragma unroll
                for (int r = 1; r < 4; ++r) {
                    acc0 += dp[2 * r + 0] * dp[2 * r + 0];
                    acc1 += dp[2 * r + 1] * dp[2 * r + 1];
                }
                f32x2 accs = acc0 + acc1;
                float p = accs[0] + accs[1];
                float pt = cross_half_sum(p);
                dens[g] = fmaf(wk, __builtin_amdgcn_exp2f(fmaf(pt, SCALE, h2)), dens[g]);
            }
        }

        // Store: half-wave h writes groups {2h, 2h+1}; zero the z==63 slice
        // (z = (g*32 + c) & 63 == 63  <=>  c==31 && g odd).
        {
            size_t vbase = (size_t)t * 128;
            float v0 = h ? dens[2] : dens[0];
            float v1 = h ? dens[3] : dens[1];
            if (c == 31) v1 = 0.f;
            out[vbase + (size_t)(h * 2 + 0) * 32 + c] = v0;
            out[vbase + (size_t)(h * 2 + 1) * 32 + c] = v1;
        }

        if (!more) break;
        t = nt;
    }
#undef ISSUE_TILE
}

extern "C" void kernel_launch(void* const* d_in, const int* in_sizes, int n_in,
                              void* d_out, int out_size, void* d_ws, size_t ws_size,
                              hipStream_t stream) {
    const float* fm = (const float*)d_in[0];
    const float* wb = (const float*)d_in[1];
    const float* mb = (const float*)d_in[2];
    const float* Lb = (const float*)d_in[3];
    const float* wf = (const float*)d_in[4];
    const float* mf = (const float*)d_in[5];
    const float* Lf = (const float*)d_in[6];
    float* out = (float*)d_out;
    (void)d_ws; (void)ws_size;   // staging lives in g_ws (module device global)

    gmm_prep_kernel<<<K_TOT, 64, 0, stream>>>(wb, mb, Lb, wf, mf, Lf);
    gmm_density_kernel<<<N_BLOCKS, THREADS, 0, stream>>>(fm, out);
}